// Round 1
// baseline (425.568 us; speedup 1.0000x reference)
//
#include <hip/hip_runtime.h>
#include <hip/hip_bf16.h>

#define BB 8
#define TT 2048
#define DD 512
#define SQRTD 22.62741699796952f

typedef float fv4 __attribute__((ext_vector_type(4)));
typedef short bv8 __attribute__((ext_vector_type(8)));
typedef short bv4 __attribute__((ext_vector_type(4)));

__device__ __forceinline__ short f2bf(float f) {
  union { float f; unsigned u; } a; a.f = f;
  unsigned u = a.u;
  u += 0x7fffu + ((u >> 16) & 1u);
  return (short)(u >> 16);
}
__device__ __forceinline__ float bf2f(short s) {
  union { unsigned u; float f; } a; a.u = ((unsigned)(unsigned short)s) << 16;
  return a.f;
}

// ---------------- K1: fused projection GEMM: C = X @ W^T (f32 in, bf16 out)
// M = B*T = 16384, N = D = 512, K = D = 512. Tile 128x128, BK=64, 4 waves.
__global__ __launch_bounds__(256, 2) void k_proj(
    const float* __restrict__ Xq, const float* __restrict__ Xk, const float* __restrict__ Xv,
    const float* __restrict__ Wq, const float* __restrict__ Wk, const float* __restrict__ Wv,
    short* __restrict__ Qb, short* __restrict__ Kb, short* __restrict__ Vb)
{
  __shared__ short At[128 * 64];
  __shared__ short Bt[128 * 64];
  const int z = blockIdx.z;
  const float* __restrict__ X = (z == 0) ? Xq : (z == 1) ? Xk : Xv;
  const float* __restrict__ W = (z == 0) ? Wq : (z == 1) ? Wk : Wv;
  short* __restrict__ C = (z == 0) ? Qb : (z == 1) ? Kb : Vb;
  const int m0 = blockIdx.x * 128;
  const int n0 = blockIdx.y * 128;
  const int t = threadIdx.x;
  const int lane = t & 63;
  const int w = t >> 6;
  const int wr = (w >> 1) * 64, wc = (w & 1) * 64;
  fv4 acc[4][4] = {};
  for (int kt = 0; kt < DD; kt += 64) {
    #pragma unroll
    for (int j = 0; j < 8; ++j) {
      int f = j * 256 + t;
      int row = f >> 4, c4 = f & 15;
      int byte = (row * 128 + c4 * 8) ^ ((row & 7) << 4);
      fv4 va = *(const fv4*)(X + (size_t)(m0 + row) * DD + kt + c4 * 4);
      bv4 ha;
      #pragma unroll
      for (int e = 0; e < 4; ++e) ha[e] = f2bf(va[e]);
      *(bv4*)((char*)At + byte) = ha;
      fv4 vb = *(const fv4*)(W + (size_t)(n0 + row) * DD + kt + c4 * 4);
      bv4 hb;
      #pragma unroll
      for (int e = 0; e < 4; ++e) hb[e] = f2bf(vb[e]);
      *(bv4*)((char*)Bt + byte) = hb;
    }
    __syncthreads();
    #pragma unroll
    for (int ks = 0; ks < 2; ++ks) {
      bv8 af[4], bfr[4];
      #pragma unroll
      for (int i = 0; i < 4; ++i) {
        int ra = wr + i * 16 + (lane & 15);
        af[i] = *(bv8*)((char*)At + ((ra * 128 + ks * 64 + ((lane >> 4) * 16)) ^ ((ra & 7) << 4)));
        int rb = wc + i * 16 + (lane & 15);
        bfr[i] = *(bv8*)((char*)Bt + ((rb * 128 + ks * 64 + ((lane >> 4) * 16)) ^ ((rb & 7) << 4)));
      }
      #pragma unroll
      for (int mi = 0; mi < 4; ++mi)
        #pragma unroll
        for (int ni = 0; ni < 4; ++ni)
          acc[mi][ni] = __builtin_amdgcn_mfma_f32_16x16x32_bf16(af[mi], bfr[ni], acc[mi][ni], 0, 0, 0);
    }
    __syncthreads();
  }
  #pragma unroll
  for (int mi = 0; mi < 4; ++mi)
    #pragma unroll
    for (int r = 0; r < 4; ++r) {
      int gm = m0 + wr + mi * 16 + ((lane >> 4) << 2) + r;
      #pragma unroll
      for (int ni = 0; ni < 4; ++ni) {
        int gn = n0 + wc + ni * 16 + (lane & 15);
        C[(size_t)gm * DD + gn] = f2bf(acc[mi][ni][r]);
      }
    }
}

// ---------------- K1b: transpose V (B,T,D) -> Vt (B,D,T), bf16
__global__ __launch_bounds__(256) void k_transpose(
    const short* __restrict__ Vb, short* __restrict__ Vt)
{
  __shared__ short tile[64][72];
  const int b = blockIdx.z;
  const int t0 = blockIdx.x * 64;  // T dim
  const int d0 = blockIdx.y * 64;  // D dim
  const int t = threadIdx.x;
  #pragma unroll
  for (int j = 0; j < 2; ++j) {
    int f = j * 256 + t;
    int row = f >> 3, c8 = f & 7;
    bv8 v = *(const bv8*)(Vb + ((size_t)b * TT + t0 + row) * DD + d0 + c8 * 8);
    *(bv8*)&tile[row][c8 * 8] = v;
  }
  __syncthreads();
  #pragma unroll
  for (int j = 0; j < 2; ++j) {
    int f = j * 256 + t;
    int drow = f >> 3, c8 = f & 7;
    bv8 v;
    #pragma unroll
    for (int e = 0; e < 8; ++e) v[e] = tile[c8 * 8 + e][drow];
    *(bv8*)(Vt + ((size_t)b * DD + d0 + drow) * TT + t0 + c8 * 8) = v;
  }
}

// ---------------- K2: S = sqrtD * Q K^T + mask ; P = exp(S) ; l = rowsum(P)
// Block: 64 q-rows (4 waves x 16 rows), loop over 8 strips of 256 keys.
__global__ __launch_bounds__(256, 2) void k_scores(
    const short* __restrict__ Qb, const short* __restrict__ Kb,
    const float* __restrict__ mask, short* __restrict__ P, float* __restrict__ lsum)
{
  __shared__ short Kt[256 * 64];
  const int b = blockIdx.y;
  const int q0 = blockIdx.x * 64;
  const int t = threadIdx.x;
  const int lane = t & 63;
  const int w = t >> 6;
  const int qrb = q0 + w * 16;
  // hoist Q fragments for this wave's 16 rows, full D=512
  bv8 qf[16];
  #pragma unroll
  for (int kk = 0; kk < 16; ++kk)
    qf[kk] = *(const bv8*)(Qb + ((size_t)b * TT + qrb + (lane & 15)) * DD + kk * 32 + (lane >> 4) * 8);
  float rsum[4] = {0.f, 0.f, 0.f, 0.f};
  for (int nt = 0; nt < 8; ++nt) {
    fv4 acc[16] = {};
    for (int kc = 0; kc < 8; ++kc) {
      #pragma unroll
      for (int j = 0; j < 8; ++j) {
        int f = j * 256 + t;
        int row = f >> 3, c8 = f & 7;
        bv8 v = *(const bv8*)(Kb + ((size_t)b * TT + nt * 256 + row) * DD + kc * 64 + c8 * 8);
        *(bv8*)((char*)Kt + ((row * 128 + c8 * 16) ^ ((row & 7) << 4))) = v;
      }
      __syncthreads();
      #pragma unroll
      for (int ks = 0; ks < 2; ++ks) {
        #pragma unroll
        for (int ni = 0; ni < 16; ++ni) {
          int row = ni * 16 + (lane & 15);
          bv8 kf = *(bv8*)((char*)Kt + ((row * 128 + ks * 64 + ((lane >> 4) * 16)) ^ ((row & 7) << 4)));
          acc[ni] = __builtin_amdgcn_mfma_f32_16x16x32_bf16(qf[kc * 2 + ks], kf, acc[ni], 0, 0, 0);
        }
      }
      __syncthreads();
    }
    // epilogue for this strip: scale + mask + exp, write P, accumulate row sums
    #pragma unroll
    for (int ni = 0; ni < 16; ++ni) {
      int key = nt * 256 + ni * 16 + (lane & 15);
      #pragma unroll
      for (int r = 0; r < 4; ++r) {
        int q = qrb + ((lane >> 4) << 2) + r;
        float s = acc[ni][r] * SQRTD + mask[((size_t)b * TT + q) * TT + key];
        float p = __expf(s);
        short pb = f2bf(p);
        P[((size_t)b * TT + q) * TT + key] = pb;
        rsum[r] += bf2f(pb);
      }
    }
  }
  #pragma unroll
  for (int off = 1; off < 16; off <<= 1) {
    #pragma unroll
    for (int r = 0; r < 4; ++r) rsum[r] += __shfl_xor(rsum[r], off);
  }
  if ((lane & 15) == 0) {
    #pragma unroll
    for (int r = 0; r < 4; ++r)
      lsum[(size_t)b * TT + qrb + ((lane >> 4) << 2) + r] = rsum[r];
  }
}

// ---------------- K3: O = (P @ Vt^T) / l  (bf16 in, f32 out)
// Per batch: M = T = 2048, N = D = 512, K = T = 2048. Tile 128x128, BK=64.
__global__ __launch_bounds__(256, 2) void k_pv(
    const short* __restrict__ P, const short* __restrict__ Vt,
    const float* __restrict__ lsum, float* __restrict__ Out)
{
  __shared__ short At[128 * 64];
  __shared__ short Bt[128 * 64];
  const int b = blockIdx.z;
  const int m0 = blockIdx.x * 128;
  const int n0 = blockIdx.y * 128;
  const int t = threadIdx.x;
  const int lane = t & 63;
  const int w = t >> 6;
  const int wr = (w >> 1) * 64, wc = (w & 1) * 64;
  fv4 acc[4][4] = {};
  for (int kt = 0; kt < TT; kt += 64) {
    #pragma unroll
    for (int j = 0; j < 4; ++j) {
      int f = j * 256 + t;
      int row = f >> 3, c8 = f & 7;
      int byte = (row * 128 + c8 * 16) ^ ((row & 7) << 4);
      bv8 va = *(const bv8*)(P + ((size_t)b * TT + m0 + row) * TT + kt + c8 * 8);
      *(bv8*)((char*)At + byte) = va;
      bv8 vb = *(const bv8*)(Vt + ((size_t)b * DD + n0 + row) * TT + kt + c8 * 8);
      *(bv8*)((char*)Bt + byte) = vb;
    }
    __syncthreads();
    #pragma unroll
    for (int ks = 0; ks < 2; ++ks) {
      bv8 af[4], bfr[4];
      #pragma unroll
      for (int i = 0; i < 4; ++i) {
        int ra = wr + i * 16 + (lane & 15);
        af[i] = *(bv8*)((char*)At + ((ra * 128 + ks * 64 + ((lane >> 4) * 16)) ^ ((ra & 7) << 4)));
        int rb = wc + i * 16 + (lane & 15);
        bfr[i] = *(bv8*)((char*)Bt + ((rb * 128 + ks * 64 + ((lane >> 4) * 16)) ^ ((rb & 7) << 4)));
      }
      #pragma unroll
      for (int mi = 0; mi < 4; ++mi)
        #pragma unroll
        for (int ni = 0; ni < 4; ++ni)
          acc[mi][ni] = __builtin_amdgcn_mfma_f32_16x16x32_bf16(af[mi], bfr[ni], acc[mi][ni], 0, 0, 0);
    }
    __syncthreads();
  }
  #pragma unroll
  for (int mi = 0; mi < 4; ++mi)
    #pragma unroll
    for (int r = 0; r < 4; ++r) {
      int gm = m0 + wr + mi * 16 + ((lane >> 4) << 2) + r;
      float inv = 1.0f / lsum[(size_t)b * TT + gm];
      #pragma unroll
      for (int ni = 0; ni < 4; ++ni) {
        int gn = n0 + wc + ni * 16 + (lane & 15);
        Out[((size_t)b * TT + gm) * DD + gn] = acc[mi][ni][r] * inv;
      }
    }
}

extern "C" void kernel_launch(void* const* d_in, const int* in_sizes, int n_in,
                              void* d_out, int out_size, void* d_ws, size_t ws_size,
                              hipStream_t stream) {
  const float* ft_q = (const float*)d_in[0];
  const float* ft_k = (const float*)d_in[1];
  const float* ft_v = (const float*)d_in[2];
  const float* mask = (const float*)d_in[3];
  const float* Wq   = (const float*)d_in[4];
  const float* Wk   = (const float*)d_in[5];
  const float* Wv   = (const float*)d_in[6];
  float* Out = (float*)d_out;

  const size_t nBTD = (size_t)BB * TT * DD;   // 8,388,608
  const size_t nBTT = (size_t)BB * TT * TT;   // 33,554,432
  short* Qb = (short*)d_ws;
  short* Kb = Qb + nBTD;
  short* Vb = Kb + nBTD;
  short* Vt = Vb + nBTD;
  short* P  = Vt + nBTD;
  float* l  = (float*)(P + nBTT);

  k_proj<<<dim3(128, 4, 3), 256, 0, stream>>>(ft_q, ft_k, ft_v, Wq, Wk, Wv, Qb, Kb, Vb);
  k_transpose<<<dim3(TT / 64, DD / 64, BB), 256, 0, stream>>>(Vb, Vt);
  k_scores<<<dim3(TT / 64, BB), 256, 0, stream>>>(Qb, Kb, mask, P, l);
  k_pv<<<dim3(TT / 128, DD / 128, BB), 256, 0, stream>>>(P, Vt, l, Out);
}

// Round 2
// 303.673 us; speedup vs baseline: 1.4014x; 1.4014x over previous
//
#include <hip/hip_runtime.h>
#include <hip/hip_bf16.h>

#define BB 8
#define TT 2048
#define DD 512
#define SQRTD 22.62741699796952f

typedef float fv4 __attribute__((ext_vector_type(4)));
typedef short bv8 __attribute__((ext_vector_type(8)));
typedef short bv4 __attribute__((ext_vector_type(4)));

__device__ __forceinline__ short f2bf(float f) {
  union { float f; unsigned u; } a; a.f = f;
  unsigned u = a.u;
  u += 0x7fffu + ((u >> 16) & 1u);
  return (short)(u >> 16);
}
__device__ __forceinline__ float bf2f(short s) {
  union { unsigned u; float f; } a; a.u = ((unsigned)(unsigned short)s) << 16;
  return a.f;
}

// ---------------- K1: fused projection GEMM: C = X @ W^T (f32 in, bf16 out)
// M = B*T = 16384, N = D = 512, K = D = 512. Tile 128x128, BK=64, 4 waves.
__global__ __launch_bounds__(256, 2) void k_proj(
    const float* __restrict__ Xq, const float* __restrict__ Xk, const float* __restrict__ Xv,
    const float* __restrict__ Wq, const float* __restrict__ Wk, const float* __restrict__ Wv,
    short* __restrict__ Qb, short* __restrict__ Kb, short* __restrict__ Vb)
{
  __shared__ short At[128 * 64];
  __shared__ short Bt[128 * 64];
  const int z = blockIdx.z;
  const float* __restrict__ X = (z == 0) ? Xq : (z == 1) ? Xk : Xv;
  const float* __restrict__ W = (z == 0) ? Wq : (z == 1) ? Wk : Wv;
  short* __restrict__ C = (z == 0) ? Qb : (z == 1) ? Kb : Vb;
  const int m0 = blockIdx.x * 128;
  const int n0 = blockIdx.y * 128;
  const int t = threadIdx.x;
  const int lane = t & 63;
  const int w = t >> 6;
  const int wr = (w >> 1) * 64, wc = (w & 1) * 64;
  fv4 acc[4][4] = {};
  for (int kt = 0; kt < DD; kt += 64) {
    #pragma unroll
    for (int j = 0; j < 8; ++j) {
      int f = j * 256 + t;
      int row = f >> 4, c4 = f & 15;
      int byte = (row * 128 + c4 * 8) ^ ((row & 7) << 4);
      fv4 va = *(const fv4*)(X + (size_t)(m0 + row) * DD + kt + c4 * 4);
      bv4 ha;
      #pragma unroll
      for (int e = 0; e < 4; ++e) ha[e] = f2bf(va[e]);
      *(bv4*)((char*)At + byte) = ha;
      fv4 vb = *(const fv4*)(W + (size_t)(n0 + row) * DD + kt + c4 * 4);
      bv4 hb;
      #pragma unroll
      for (int e = 0; e < 4; ++e) hb[e] = f2bf(vb[e]);
      *(bv4*)((char*)Bt + byte) = hb;
    }
    __syncthreads();
    #pragma unroll
    for (int ks = 0; ks < 2; ++ks) {
      bv8 af[4], bfr[4];
      #pragma unroll
      for (int i = 0; i < 4; ++i) {
        int ra = wr + i * 16 + (lane & 15);
        af[i] = *(bv8*)((char*)At + ((ra * 128 + ks * 64 + ((lane >> 4) * 16)) ^ ((ra & 7) << 4)));
        int rb = wc + i * 16 + (lane & 15);
        bfr[i] = *(bv8*)((char*)Bt + ((rb * 128 + ks * 64 + ((lane >> 4) * 16)) ^ ((rb & 7) << 4)));
      }
      #pragma unroll
      for (int mi = 0; mi < 4; ++mi)
        #pragma unroll
        for (int ni = 0; ni < 4; ++ni)
          acc[mi][ni] = __builtin_amdgcn_mfma_f32_16x16x32_bf16(af[mi], bfr[ni], acc[mi][ni], 0, 0, 0);
    }
    __syncthreads();
  }
  #pragma unroll
  for (int mi = 0; mi < 4; ++mi)
    #pragma unroll
    for (int r = 0; r < 4; ++r) {
      int gm = m0 + wr + mi * 16 + ((lane >> 4) << 2) + r;
      #pragma unroll
      for (int ni = 0; ni < 4; ++ni) {
        int gn = n0 + wc + ni * 16 + (lane & 15);
        C[(size_t)gm * DD + gn] = f2bf(acc[mi][ni][r]);
      }
    }
}

// ---------------- K1b: transpose V (B,T,D) -> Vt (B,D,T), bf16
__global__ __launch_bounds__(256) void k_transpose(
    const short* __restrict__ Vb, short* __restrict__ Vt)
{
  __shared__ short tile[64][72];
  const int b = blockIdx.z;
  const int t0 = blockIdx.x * 64;  // T dim
  const int d0 = blockIdx.y * 64;  // D dim
  const int t = threadIdx.x;
  #pragma unroll
  for (int j = 0; j < 2; ++j) {
    int f = j * 256 + t;
    int row = f >> 3, c8 = f & 7;
    bv8 v = *(const bv8*)(Vb + ((size_t)b * TT + t0 + row) * DD + d0 + c8 * 8);
    *(bv8*)&tile[row][c8 * 8] = v;
  }
  __syncthreads();
  #pragma unroll
  for (int j = 0; j < 2; ++j) {
    int f = j * 256 + t;
    int drow = f >> 3, c8 = f & 7;
    bv8 v;
    #pragma unroll
    for (int e = 0; e < 8; ++e) v[e] = tile[c8 * 8 + e][drow];
    *(bv8*)(Vt + ((size_t)b * DD + d0 + drow) * TT + t0 + c8 * 8) = v;
  }
}

// ---------------- K2: fused attention: S = sqrtD*QK^T + mask; P = exp(S);
// O = (P @ V) / rowsum(P).  Block: 64 q-rows, 8 waves, strips of 32 keys.
// Wave w: QK^T tile (rows 16*(w>>1), keys 16*(w&1) in strip); PV d-cols [64w,64w+64).
__global__ __launch_bounds__(512, 2) void k_attn(
    const short* __restrict__ Qb, const short* __restrict__ Kb,
    const short* __restrict__ Vt, const float* __restrict__ mask,
    float* __restrict__ Out)
{
  __shared__ short Ks[32 * 512];   // 32 KB, swizzled rows of 1 KB
  __shared__ short Ps[64 * 32];    // 4 KB, swizzled rows of 64 B
  __shared__ float ls[4][2][16];
  const int b = blockIdx.y;
  const int q0 = blockIdx.x * 64;
  const int t = threadIdx.x;
  const int lane = t & 63;
  const int w = t >> 6;
  const int rg = w >> 1;      // row group 0..3
  const int kg = w & 1;       // key sub-tile 0..1
  const int l15 = lane & 15;
  const int l4 = lane >> 4;   // 0..3

  // hoist Q fragments: rows q0+16rg..+15, full D=512 (static unroll -> registers)
  bv8 qf[16];
  #pragma unroll
  for (int kk = 0; kk < 16; ++kk)
    qf[kk] = *(const bv8*)(Qb + ((size_t)b * TT + q0 + rg * 16 + l15) * DD + kk * 32 + l4 * 8);

  fv4 o[4][4] = {};
  float rsum[4] = {0.f, 0.f, 0.f, 0.f};

  for (int nt = 0; nt < TT / 32; ++nt) {
    // stage K strip (32 keys x 512 d), XOR-swizzled
    #pragma unroll
    for (int j = 0; j < 4; ++j) {
      int f = j * 512 + t;
      int row = f >> 6, slot = f & 63;
      bv8 v = *(const bv8*)(Kb + ((size_t)b * TT + nt * 32 + row) * DD + slot * 8);
      *(bv8*)((char*)Ks + row * 1024 + ((slot * 16) ^ ((row & 7) << 4))) = v;
    }
    // prefetch mask values for this wave's S tile (hide latency under sync+QK)
    float mk[4];
    #pragma unroll
    for (int r = 0; r < 4; ++r) {
      int row = rg * 16 + l4 * 4 + r;
      mk[r] = mask[((size_t)b * TT + q0 + row) * TT + nt * 32 + kg * 16 + l15];
    }
    __syncthreads();
    // QK^T: one 16x16 tile per wave, K = 512
    fv4 sa = {};
    #pragma unroll
    for (int kk = 0; kk < 16; ++kk) {
      int krow = kg * 16 + l15;
      bv8 kf = *(const bv8*)((const char*)Ks + krow * 1024 + ((kk * 64 + l4 * 16) ^ ((krow & 7) << 4)));
      sa = __builtin_amdgcn_mfma_f32_16x16x32_bf16(qf[kk], kf, sa, 0, 0, 0);
    }
    // epilogue: scale + mask + exp -> P (LDS, swizzled), partial row sums
    #pragma unroll
    for (int r = 0; r < 4; ++r) {
      int row = rg * 16 + l4 * 4 + r;
      float s = sa[r] * SQRTD + mk[r];
      float p = __expf(s);
      short pb = f2bf(p);
      rsum[r] += bf2f(pb);
      int col = kg * 16 + l15;
      *((short*)((char*)Ps + ((row * 64 + col * 2) ^ ((row & 7) << 4)))) = pb;
    }
    __syncthreads();
    // PV: wave w owns d-cols [64w, 64w+64), k = 32 keys of this strip
    bv8 vf[4];
    #pragma unroll
    for (int ni = 0; ni < 4; ++ni)
      vf[ni] = *(const bv8*)(Vt + ((size_t)b * DD + w * 64 + ni * 16 + l15) * TT + nt * 32 + l4 * 8);
    #pragma unroll
    for (int mi = 0; mi < 4; ++mi) {
      int prow = mi * 16 + l15;
      bv8 pa = *(const bv8*)((const char*)Ps + ((prow * 64 + l4 * 16) ^ ((prow & 7) << 4)));
      #pragma unroll
      for (int ni = 0; ni < 4; ++ni)
        o[mi][ni] = __builtin_amdgcn_mfma_f32_16x16x32_bf16(pa, vf[ni], o[mi][ni], 0, 0, 0);
    }
  }

  // final row-sum reduction: over 16 key-residues (lanes) then over kg waves
  #pragma unroll
  for (int r = 0; r < 4; ++r) {
    float v = rsum[r];
    v += __shfl_xor(v, 1);
    v += __shfl_xor(v, 2);
    v += __shfl_xor(v, 4);
    v += __shfl_xor(v, 8);
    if (l15 == 0) ls[rg][kg][l4 * 4 + r] = v;
  }
  __syncthreads();
  // write O / l
  #pragma unroll
  for (int mi = 0; mi < 4; ++mi)
    #pragma unroll
    for (int r = 0; r < 4; ++r) {
      int idx = l4 * 4 + r;
      float inv = 1.0f / (ls[mi][0][idx] + ls[mi][1][idx]);
      int grow = q0 + mi * 16 + idx;
      #pragma unroll
      for (int ni = 0; ni < 4; ++ni)
        Out[((size_t)b * TT + grow) * DD + w * 64 + ni * 16 + l15] = o[mi][ni][r] * inv;
    }
}

extern "C" void kernel_launch(void* const* d_in, const int* in_sizes, int n_in,
                              void* d_out, int out_size, void* d_ws, size_t ws_size,
                              hipStream_t stream) {
  const float* ft_q = (const float*)d_in[0];
  const float* ft_k = (const float*)d_in[1];
  const float* ft_v = (const float*)d_in[2];
  const float* mask = (const float*)d_in[3];
  const float* Wq   = (const float*)d_in[4];
  const float* Wk   = (const float*)d_in[5];
  const float* Wv   = (const float*)d_in[6];
  float* Out = (float*)d_out;

  const size_t nBTD = (size_t)BB * TT * DD;   // 8,388,608
  short* Qb = (short*)d_ws;
  short* Kb = Qb + nBTD;
  short* Vb = Kb + nBTD;
  short* Vt = Vb + nBTD;

  k_proj<<<dim3(128, 4, 3), 256, 0, stream>>>(ft_q, ft_k, ft_v, Wq, Wk, Wv, Qb, Kb, Vb);
  k_transpose<<<dim3(TT / 64, DD / 64, BB), 256, 0, stream>>>(Vb, Vt);
  k_attn<<<dim3(TT / 64, BB), 512, 0, stream>>>(Qb, Kb, Vt, mask, Out);
}

// Round 3
// 246.979 us; speedup vs baseline: 1.7231x; 1.2296x over previous
//
#include <hip/hip_runtime.h>
#include <hip/hip_bf16.h>

#define BB 8
#define TT 2048
#define DD 512
#define SQRTD 22.62741699796952f

typedef float fv4 __attribute__((ext_vector_type(4)));
typedef short bv8 __attribute__((ext_vector_type(8)));
typedef short bv4 __attribute__((ext_vector_type(4)));

__device__ __forceinline__ short f2bf(float f) {
  __hip_bfloat16 h = __float2bfloat16(f);   // RNE; compiler packs to v_cvt_pk_bf16_f32
  return *reinterpret_cast<short*>(&h);
}
__device__ __forceinline__ float bf2f(short s) {
  union { unsigned u; float f; } a; a.u = ((unsigned)(unsigned short)s) << 16;
  return a.f;
}

// ---------------- K1: fused projection GEMM: C = X @ W^T (f32 in, bf16 out)
__global__ __launch_bounds__(256, 2) void k_proj(
    const float* __restrict__ Xq, const float* __restrict__ Xk, const float* __restrict__ Xv,
    const float* __restrict__ Wq, const float* __restrict__ Wk, const float* __restrict__ Wv,
    short* __restrict__ Qb, short* __restrict__ Kb, short* __restrict__ Vb)
{
  __shared__ short At[128 * 64];
  __shared__ short Bt[128 * 64];
  const int z = blockIdx.z;
  const float* __restrict__ X = (z == 0) ? Xq : (z == 1) ? Xk : Xv;
  const float* __restrict__ W = (z == 0) ? Wq : (z == 1) ? Wk : Wv;
  short* __restrict__ C = (z == 0) ? Qb : (z == 1) ? Kb : Vb;
  const int m0 = blockIdx.x * 128;
  const int n0 = blockIdx.y * 128;
  const int t = threadIdx.x;
  const int lane = t & 63;
  const int w = t >> 6;
  const int wr = (w >> 1) * 64, wc = (w & 1) * 64;
  fv4 acc[4][4] = {};
  for (int kt = 0; kt < DD; kt += 64) {
    #pragma unroll
    for (int j = 0; j < 8; ++j) {
      int f = j * 256 + t;
      int row = f >> 4, c4 = f & 15;
      int byte = (row * 128 + c4 * 8) ^ ((row & 7) << 4);
      fv4 va = *(const fv4*)(X + (size_t)(m0 + row) * DD + kt + c4 * 4);
      bv4 ha;
      #pragma unroll
      for (int e = 0; e < 4; ++e) ha[e] = f2bf(va[e]);
      *(bv4*)((char*)At + byte) = ha;
      fv4 vb = *(const fv4*)(W + (size_t)(n0 + row) * DD + kt + c4 * 4);
      bv4 hb;
      #pragma unroll
      for (int e = 0; e < 4; ++e) hb[e] = f2bf(vb[e]);
      *(bv4*)((char*)Bt + byte) = hb;
    }
    __syncthreads();
    #pragma unroll
    for (int ks = 0; ks < 2; ++ks) {
      bv8 af[4], bfr[4];
      #pragma unroll
      for (int i = 0; i < 4; ++i) {
        int ra = wr + i * 16 + (lane & 15);
        af[i] = *(bv8*)((char*)At + ((ra * 128 + ks * 64 + ((lane >> 4) * 16)) ^ ((ra & 7) << 4)));
        int rb = wc + i * 16 + (lane & 15);
        bfr[i] = *(bv8*)((char*)Bt + ((rb * 128 + ks * 64 + ((lane >> 4) * 16)) ^ ((rb & 7) << 4)));
      }
      #pragma unroll
      for (int mi = 0; mi < 4; ++mi)
        #pragma unroll
        for (int ni = 0; ni < 4; ++ni)
          acc[mi][ni] = __builtin_amdgcn_mfma_f32_16x16x32_bf16(af[mi], bfr[ni], acc[mi][ni], 0, 0, 0);
    }
    __syncthreads();
  }
  #pragma unroll
  for (int mi = 0; mi < 4; ++mi)
    #pragma unroll
    for (int r = 0; r < 4; ++r) {
      int gm = m0 + wr + mi * 16 + ((lane >> 4) << 2) + r;
      #pragma unroll
      for (int ni = 0; ni < 4; ++ni) {
        int gn = n0 + wc + ni * 16 + (lane & 15);
        C[(size_t)gm * DD + gn] = f2bf(acc[mi][ni][r]);
      }
    }
}

// ---------------- K1b: transpose V (B,T,D) -> Vt (B,D,T), bf16
__global__ __launch_bounds__(256) void k_transpose(
    const short* __restrict__ Vb, short* __restrict__ Vt)
{
  __shared__ short tile[64][72];
  const int b = blockIdx.z;
  const int t0 = blockIdx.x * 64;
  const int d0 = blockIdx.y * 64;
  const int t = threadIdx.x;
  #pragma unroll
  for (int j = 0; j < 2; ++j) {
    int f = j * 256 + t;
    int row = f >> 3, c8 = f & 7;
    bv8 v = *(const bv8*)(Vb + ((size_t)b * TT + t0 + row) * DD + d0 + c8 * 8);
    *(bv8*)&tile[row][c8 * 8] = v;
  }
  __syncthreads();
  #pragma unroll
  for (int j = 0; j < 2; ++j) {
    int f = j * 256 + t;
    int drow = f >> 3, c8 = f & 7;
    bv8 v;
    #pragma unroll
    for (int e = 0; e < 8; ++e) v[e] = tile[c8 * 8 + e][drow];
    *(bv8*)(Vt + ((size_t)b * DD + d0 + drow) * TT + t0 + c8 * 8) = v;
  }
}

// ---------------- K2: fused attention, pipelined.
// Block: 64 q-rows, 8 waves (4 row-groups x 2 key-groups), KV strips of 32.
// Per strip: issue mask(t+1)/V(t)/K(t+1) loads early; QK from LDS (4 acc chains);
// raw barriers (no vmcnt drain); ds_write K(t+1) after bar1; PV from regs+Ps.
__global__ __launch_bounds__(512, 2) void k_attn(
    const short* __restrict__ Qb, const short* __restrict__ Kb,
    const short* __restrict__ Vt, const float* __restrict__ mask,
    float* __restrict__ Out)
{
  __shared__ short Ks[32 * 512];   // 32 KB, row stride 1 KB, XOR-swizzled
  __shared__ short Ps[64 * 32];    // 4 KB, row stride 64 B, XOR-swizzled
  __shared__ float ls[4][2][16];
  const int b = blockIdx.x;        // batch on x => linear_id % 8 == b => XCD-pinned
  const int q0 = blockIdx.y * 64;
  const int t = threadIdx.x;
  const int lane = t & 63;
  const int w = t >> 6;
  const int rg = w >> 1;
  const int kg = w & 1;
  const int l15 = lane & 15;
  const int l4 = lane >> 4;

  const short* __restrict__ Kbase = Kb + (size_t)b * TT * DD;
  const float* __restrict__ Mbase = mask + ((size_t)b * TT + q0) * TT;

  // hoist Q fragments (16 rows per wave, full D=512)
  bv8 qf[16];
  #pragma unroll
  for (int kk = 0; kk < 16; ++kk)
    qf[kk] = *(const bv8*)(Qb + ((size_t)b * TT + q0 + rg * 16 + l15) * DD + kk * 32 + l4 * 8);

  fv4 o[4][4] = {};
  float rsum[4] = {0.f, 0.f, 0.f, 0.f};

  // prologue: stage K strip 0 via regs -> swizzled LDS
  {
    bv8 k0[4];
    #pragma unroll
    for (int c = 0; c < 4; ++c) k0[c] = *(const bv8*)(Kbase + t * 32 + c * 8);
    #pragma unroll
    for (int c = 0; c < 4; ++c) {
      int g = t * 64 + c * 16;
      int row = g >> 10, slot = (g >> 4) & 63;
      *(bv8*)((char*)Ks + row * 1024 + ((slot * 16) ^ ((row & 7) << 4))) = k0[c];
    }
  }
  // prologue: mask(0)
  float mko[4], mkn[4];
  #pragma unroll
  for (int r = 0; r < 4; ++r)
    mko[r] = Mbase[(size_t)(rg * 16 + l4 * 4 + r) * TT + kg * 16 + l15];
  asm volatile("s_waitcnt lgkmcnt(0)\n\ts_barrier" ::: "memory");

  for (int nt = 0; nt < TT / 32; ++nt) {
    const int ntn = (nt + 1) & (TT / 32 - 1);
    // ---- issue next-strip / this-strip loads (stay in flight across barriers)
    #pragma unroll
    for (int r = 0; r < 4; ++r)
      mkn[r] = Mbase[(size_t)(rg * 16 + l4 * 4 + r) * TT + ntn * 32 + kg * 16 + l15];
    bv8 vreg[4];
    #pragma unroll
    for (int ni = 0; ni < 4; ++ni)
      vreg[ni] = *(const bv8*)(Vt + ((size_t)b * DD + w * 64 + ni * 16 + l15) * TT + nt * 32 + l4 * 8);
    bv8 kreg[4];
    #pragma unroll
    for (int c = 0; c < 4; ++c)
      kreg[c] = *(const bv8*)(Kbase + (size_t)ntn * 32 * DD + t * 32 + c * 8);

    // ---- QK^T: 16x16 tile per wave, 4 independent accumulator chains
    fv4 s0 = {}, s1 = {}, s2 = {}, s3 = {};
    const int krow = kg * 16 + l15;
    const int ksw = (krow & 7) << 4;
    __builtin_amdgcn_s_setprio(1);
    #pragma unroll
    for (int kk = 0; kk < 16; kk += 4) {
      bv8 kf0 = *(const bv8*)((const char*)Ks + krow * 1024 + (((kk + 0) * 64 + l4 * 16) ^ ksw));
      bv8 kf1 = *(const bv8*)((const char*)Ks + krow * 1024 + (((kk + 1) * 64 + l4 * 16) ^ ksw));
      bv8 kf2 = *(const bv8*)((const char*)Ks + krow * 1024 + (((kk + 2) * 64 + l4 * 16) ^ ksw));
      bv8 kf3 = *(const bv8*)((const char*)Ks + krow * 1024 + (((kk + 3) * 64 + l4 * 16) ^ ksw));
      s0 = __builtin_amdgcn_mfma_f32_16x16x32_bf16(qf[kk + 0], kf0, s0, 0, 0, 0);
      s1 = __builtin_amdgcn_mfma_f32_16x16x32_bf16(qf[kk + 1], kf1, s1, 0, 0, 0);
      s2 = __builtin_amdgcn_mfma_f32_16x16x32_bf16(qf[kk + 2], kf2, s2, 0, 0, 0);
      s3 = __builtin_amdgcn_mfma_f32_16x16x32_bf16(qf[kk + 3], kf3, s3, 0, 0, 0);
    }
    __builtin_amdgcn_s_setprio(0);
    fv4 sa = (s0 + s1) + (s2 + s3);

    // ---- epilogue: scale + mask + exp -> Ps (swizzled), partial row sums
    #pragma unroll
    for (int r = 0; r < 4; ++r) {
      int row = rg * 16 + l4 * 4 + r;
      float s = sa[r] * SQRTD + mko[r];
      float p = __expf(s);
      short pb = f2bf(p);
      rsum[r] += bf2f(pb);
      *((short*)((char*)Ps + ((row * 64 + (kg * 16 + l15) * 2) ^ ((row & 7) << 4)))) = pb;
    }
    #pragma unroll
    for (int r = 0; r < 4; ++r) mko[r] = mkn[r];

    // bar1: Ps visible; all waves done reading Ks(t). K(t+1)/V still in flight.
    asm volatile("s_waitcnt lgkmcnt(0)\n\ts_barrier" ::: "memory");

    // ---- write K(t+1) into Ks (compiler inserts vmcnt wait for kreg)
    #pragma unroll
    for (int c = 0; c < 4; ++c) {
      int g = t * 64 + c * 16;
      int row = g >> 10, slot = (g >> 4) & 63;
      *(bv8*)((char*)Ks + row * 1024 + ((slot * 16) ^ ((row & 7) << 4))) = kreg[c];
    }

    // ---- PV: wave w owns d-cols [64w, 64w+64)
    __builtin_amdgcn_s_setprio(1);
    #pragma unroll
    for (int mi = 0; mi < 4; ++mi) {
      int prow = mi * 16 + l15;
      bv8 pa = *(const bv8*)((const char*)Ps + ((prow * 64 + l4 * 16) ^ ((prow & 7) << 4)));
      #pragma unroll
      for (int ni = 0; ni < 4; ++ni)
        o[mi][ni] = __builtin_amdgcn_mfma_f32_16x16x32_bf16(pa, vreg[ni], o[mi][ni], 0, 0, 0);
    }
    __builtin_amdgcn_s_setprio(0);

    // bar2: Ks(t+1) writes visible before next QK; Ps reads done before next write.
    asm volatile("s_waitcnt lgkmcnt(0)\n\ts_barrier" ::: "memory");
  }

  // final row-sum reduction across 16 key-residues, then across kg waves
  #pragma unroll
  for (int r = 0; r < 4; ++r) {
    float v = rsum[r];
    v += __shfl_xor(v, 1);
    v += __shfl_xor(v, 2);
    v += __shfl_xor(v, 4);
    v += __shfl_xor(v, 8);
    if (l15 == 0) ls[rg][kg][l4 * 4 + r] = v;
  }
  __syncthreads();
  #pragma unroll
  for (int mi = 0; mi < 4; ++mi)
    #pragma unroll
    for (int r = 0; r < 4; ++r) {
      int idx = l4 * 4 + r;
      float inv = 1.0f / (ls[mi][0][idx] + ls[mi][1][idx]);
      int grow = q0 + mi * 16 + idx;
      #pragma unroll
      for (int ni = 0; ni < 4; ++ni)
        Out[((size_t)b * TT + grow) * DD + w * 64 + ni * 16 + l15] = o[mi][ni][r] * inv;
    }
}

extern "C" void kernel_launch(void* const* d_in, const int* in_sizes, int n_in,
                              void* d_out, int out_size, void* d_ws, size_t ws_size,
                              hipStream_t stream) {
  const float* ft_q = (const float*)d_in[0];
  const float* ft_k = (const float*)d_in[1];
  const float* ft_v = (const float*)d_in[2];
  const float* mask = (const float*)d_in[3];
  const float* Wq   = (const float*)d_in[4];
  const float* Wk   = (const float*)d_in[5];
  const float* Wv   = (const float*)d_in[6];
  float* Out = (float*)d_out;

  const size_t nBTD = (size_t)BB * TT * DD;
  short* Qb = (short*)d_ws;
  short* Kb = Qb + nBTD;
  short* Vb = Kb + nBTD;
  short* Vt = Vb + nBTD;

  k_proj<<<dim3(128, 4, 3), 256, 0, stream>>>(ft_q, ft_k, ft_v, Wq, Wk, Wv, Qb, Kb, Vb);
  k_transpose<<<dim3(TT / 64, DD / 64, BB), 256, 0, stream>>>(Vb, Vt);
  k_attn<<<dim3(BB, TT / 64), 512, 0, stream>>>(Qb, Kb, Vt, mask, Out);
}